// Round 2
// baseline (90964.496 us; speedup 1.0000x reference)
//
#include <hip/hip_runtime.h>
#include <hip/hip_fp16.h>

// GRU 2-layer, B=256 S=1024 F=75 H=256.
// Round 2: LDS-resident weight slices + cross-block group h-exchange.
//   16 groups (16 batch rows each) x 16 blocks (16 hidden units each) = 256 blocks,
//   256 threads = (row 0..15, unit 0..15). Weight slice (82KB) lives in LDS.
//   Per step: layer0 slice -> publish h0 -> group barrier -> gather h0 ->
//             layer1 slice -> publish h1 -> group barrier -> gather h1.
//   Flags: monotonic counters in d_ws, memset to 0 each launch. Spin bailout latch
//   guarantees no hang even if co-residency/sync breaks (fails absmax instead).

#define NS 1024
#define NF 75
#define NH 256

#define W0I_U_STRIDE 240                 // 10 chunks * 24 halves
#define W0I_SIZE (16 * W0I_U_STRIDE)     // 3840
#define WH_U_STRIDE 776                  // 32 chunks * 24 + 8 pad halves
#define WH_SIZE (16 * WH_U_STRIDE)       // 12416
#define IMG_HALVES (W0I_SIZE + 3 * WH_SIZE)  // 41088 halves = 82176 B per block image

#define HROW 264                         // h LDS row stride (halves): 528B -> 2-way max
#define XROW 88                          // x LDS row stride (halves): 176B -> 2-way max

// d_ws layout (bytes)
#define FLAGS_BYTES 4096                                  // f0 @0 (1KB), f1 @1024
#define WIMG_OFF 4096
#define WIMG_BYTES (16 * IMG_HALVES * 2)                  // 1,314,816
#define HX0_OFF (WIMG_OFF + WIMG_BYTES)
#define HX_BYTES (16 * 16 * NH * 2)                       // 131072
#define HX1_OFF (HX0_OFF + HX_BYTES)

typedef _Float16 half2_raw __attribute__((ext_vector_type(2)));

__device__ __forceinline__ float fdot2f(__half2 a, __half2 b, float c) {
  return __builtin_amdgcn_fdot2(__builtin_bit_cast(half2_raw, a),
                                __builtin_bit_cast(half2_raw, b), c, false);
}

union V8 { float4 f; __half2 h[4]; };

__device__ __forceinline__ void chunk3(const __half* __restrict__ w,
                                       const __half* __restrict__ v,
                                       float& a0, float& a1, float& a2) {
  V8 w0, w1, w2, hv;
  w0.f = *(const float4*)(w);
  w1.f = *(const float4*)(w + 8);
  w2.f = *(const float4*)(w + 16);
  hv.f = *(const float4*)(v);
  #pragma unroll
  for (int q = 0; q < 4; ++q) {
    a0 = fdot2f(w0.h[q], hv.h[q], a0);
    a1 = fdot2f(w1.h[q], hv.h[q], a1);
    a2 = fdot2f(w2.h[q], hv.h[q], a2);
  }
}

// Build per-block LDS weight images in d_ws.
// Image j (unit slice j*16..j*16+15):
//   [0,3840): w0i  as [u][10 chunks][3 gates][8 halves] (c>=75 zero)
//   [3840,16256): w0h as [u][32 chunks][3][8] + 8 pad halves per u
//   [16256,28672): w1i same
//   [28672,41088): w1h same
__global__ void prep_wimg(const float* __restrict__ wih0, const float* __restrict__ whh0,
                          const float* __restrict__ wih1, const float* __restrict__ whh1,
                          __half* __restrict__ wimg) {
  const long total = 16L * IMG_HALVES;
  for (long i = (long)blockIdx.x * blockDim.x + threadIdx.x; i < total;
       i += (long)gridDim.x * blockDim.x) {
    const int j = (int)(i / IMG_HALVES);
    const int rem = (int)(i - (long)j * IMG_HALVES);
    float val = 0.f;
    if (rem < W0I_SIZE) {
      const int u = rem / W0I_U_STRIDE, rr = rem % W0I_U_STRIDE;
      const int cc = rr / 24, w = rr % 24, g = w >> 3, e = w & 7;
      const int c = cc * 8 + e;
      if (c < NF) val = wih0[(g * NH + j * 16 + u) * NF + c];
    } else {
      const int rem2 = rem - W0I_SIZE;
      const int m = rem2 / WH_SIZE;
      const int rr2 = rem2 - m * WH_SIZE;
      const int u = rr2 / WH_U_STRIDE, q = rr2 % WH_U_STRIDE;
      if (q < 768) {
        const int cc = q / 24, w = q % 24, g = w >> 3, e = w & 7;
        const int c = cc * 8 + e;
        const float* src = (m == 0) ? whh0 : (m == 1) ? wih1 : whh1;
        val = src[(g * NH + j * 16 + u) * NH + c];
      }
    }
    wimg[i] = __float2half(val);
  }
}

__global__ __launch_bounds__(256, 1) void gru_group(
    const float* __restrict__ x,
    const float* __restrict__ b_ih0, const float* __restrict__ b_hh0,
    const float* __restrict__ b_ih1, const float* __restrict__ b_hh1,
    const float* __restrict__ w_lin, const float* __restrict__ b_lin,
    const __half* __restrict__ wimg,
    __half* __restrict__ hx0, __half* __restrict__ hx1,
    unsigned* __restrict__ f0, unsigned* __restrict__ f1,
    float* __restrict__ out)
{
  const int tid = threadIdx.x;
  const int bid = blockIdx.x;
  // XCD-local grouping heuristic (round-robin dispatch): performance-only.
  const int gr = (bid & 7) + ((bid >> 7) << 3);   // group 0..15 (rows gr*16..+15)
  const int j  = (bid >> 3) & 15;                 // member: units j*16..+15
  const int r  = tid & 15;                        // local row
  const int u  = tid >> 4;                        // local unit
  const int gu = j * 16 + u;                      // global unit

  __shared__ __half wimg_s[IMG_HALVES];
  __shared__ __half h0p[16 * HROW];
  __shared__ __half h1p[16 * HROW];
  __shared__ __half xs_flat[2 * 16 * XROW];
  __shared__ float  red[16][17];

  // ---- load weight image ----
  {
    const float4* src = (const float4*)(wimg + (long)j * IMG_HALVES);
    float4* dst = (float4*)wimg_s;
    for (int i = tid; i < IMG_HALVES / 8; i += 256) dst[i] = src[i];
  }
  // ---- zero h and x LDS ----
  for (int i = tid; i < 16 * HROW; i += 256) { h0p[i] = __float2half(0.f); h1p[i] = __float2half(0.f); }
  for (int i = tid; i < 2 * 16 * XROW; i += 256) xs_flat[i] = __float2half(0.f);

  // ---- per-thread x-load mapping (5 slots covering 16 rows x 75 cols) ----
  int xr_[5], xc_[5]; bool xv_[5];
  #pragma unroll
  for (int i = 0; i < 5; ++i) {
    const int idx = i * 256 + tid;
    xv_[i] = idx < 16 * NF;
    xr_[i] = xv_[i] ? idx / NF : 0;
    xc_[i] = xv_[i] ? idx % NF : 0;
  }
  const float* __restrict__ xbase = x + (size_t)(gr * 16) * NS * NF;
  // t=0 into buffer 0
  #pragma unroll
  for (int i = 0; i < 5; ++i)
    if (xv_[i]) xs_flat[xr_[i] * XROW + xc_[i]] =
        __float2half(xbase[(size_t)xr_[i] * NS * NF + xc_[i]]);

  // ---- biases ----
  const float cbr0 = b_ih0[gu] + b_hh0[gu];
  const float cbz0 = b_ih0[NH + gu] + b_hh0[NH + gu];
  const float bnx0 = b_ih0[2 * NH + gu];
  const float bnh0 = b_hh0[2 * NH + gu];
  const float cbr1 = b_ih1[gu] + b_hh1[gu];
  const float cbz1 = b_ih1[NH + gu] + b_hh1[NH + gu];
  const float bnx1 = b_ih1[2 * NH + gu];
  const float bnh1 = b_hh1[2 * NH + gu];

  const __half* __restrict__ w0i_u = wimg_s + u * W0I_U_STRIDE;
  const __half* __restrict__ w0h_u = wimg_s + W0I_SIZE + u * WH_U_STRIDE;
  const __half* __restrict__ w1i_u = wimg_s + W0I_SIZE + WH_SIZE + u * WH_U_STRIDE;
  const __half* __restrict__ w1h_u = wimg_s + W0I_SIZE + 2 * WH_SIZE + u * WH_U_STRIDE;

  __half* __restrict__ hx0g = hx0 + gr * (16 * NH);
  __half* __restrict__ hx1g = hx1 + gr * (16 * NH);
  unsigned* __restrict__ f0g = f0 + gr * 16;
  unsigned* __restrict__ f1g = f1 + gr * 16;

  float h0f = 0.f, h1f = 0.f;
  int dead = 0, spins = 0;

  __syncthreads();

  for (int t = 0; t < NS; ++t) {
    // prefetch x[t+1] into regs
    float xf[5];
    if (t + 1 < NS) {
      #pragma unroll
      for (int i = 0; i < 5; ++i)
        if (xv_[i]) xf[i] = xbase[((size_t)xr_[i] * NS + (t + 1)) * NF + xc_[i]];
    }

    // ---- P2: layer 0 ----
    float ar = cbr0, az = cbz0, anx = bnx0, anh = bnh0;
    {
      const __half* xp = xs_flat + (t & 1) * (16 * XROW) + r * XROW;
      #pragma unroll 5
      for (int cc = 0; cc < 10; ++cc)
        chunk3(w0i_u + cc * 24, xp + cc * 8, ar, az, anx);
      const __half* hp = h0p + r * HROW;
      #pragma unroll 8
      for (int cc = 0; cc < 32; ++cc)
        chunk3(w0h_u + cc * 24, hp + cc * 8, ar, az, anh);
    }
    {
      const float rg = 1.f / (1.f + __expf(-ar));
      const float zg = 1.f / (1.f + __expf(-az));
      const float ng = tanhf(anx + rg * anh);
      h0f = (1.f - zg) * ng + zg * h0f;
    }

    // ---- P3: publish h0 slice ----
    hx0g[r * NH + gu] = __float2half(h0f);
    __threadfence();
    __syncthreads();
    if (tid == 0)
      __hip_atomic_store(&f0g[j], (unsigned)(t + 1), __ATOMIC_RELAXED,
                         __HIP_MEMORY_SCOPE_AGENT);

    // ---- P4: wait + gather full h0 ----
    if (tid < 16) {
      while (!dead && __hip_atomic_load(&f0g[tid], __ATOMIC_RELAXED,
                                        __HIP_MEMORY_SCOPE_AGENT) < (unsigned)(t + 1)) {
        if (++spins > 2000000) dead = 1;
        __builtin_amdgcn_s_sleep(1);
      }
    }
    __syncthreads();
    __threadfence();
    for (int i = tid; i < 512; i += 256) {
      const int rr = i >> 5, c8 = i & 31;
      const float4 v = *(const float4*)(hx0g + rr * NH + c8 * 8);
      *(float4*)(h0p + rr * HROW + c8 * 8) = v;
    }
    __syncthreads();

    // ---- P5: layer 1 ----
    ar = cbr1; az = cbz1; anx = bnx1; anh = bnh1;
    {
      const __half* hp = h0p + r * HROW;
      #pragma unroll 8
      for (int cc = 0; cc < 32; ++cc)
        chunk3(w1i_u + cc * 24, hp + cc * 8, ar, az, anx);
      const __half* hq = h1p + r * HROW;
      #pragma unroll 8
      for (int cc = 0; cc < 32; ++cc)
        chunk3(w1h_u + cc * 24, hq + cc * 8, ar, az, anh);
    }
    {
      const float rg = 1.f / (1.f + __expf(-ar));
      const float zg = 1.f / (1.f + __expf(-az));
      const float ng = tanhf(anx + rg * anh);
      h1f = (1.f - zg) * ng + zg * h1f;
    }
    // stage x[t+1] into the other xs buffer
    if (t + 1 < NS) {
      #pragma unroll
      for (int i = 0; i < 5; ++i)
        if (xv_[i]) xs_flat[((t + 1) & 1) * (16 * XROW) + xr_[i] * XROW + xc_[i]] =
            __float2half(xf[i]);
    }

    // ---- P6: publish h1 slice ----
    hx1g[r * NH + gu] = __float2half(h1f);
    __threadfence();
    __syncthreads();
    if (tid == 0)
      __hip_atomic_store(&f1g[j], (unsigned)(t + 1), __ATOMIC_RELAXED,
                         __HIP_MEMORY_SCOPE_AGENT);

    // ---- P7: wait + gather full h1 ----
    if (tid < 16) {
      while (!dead && __hip_atomic_load(&f1g[tid], __ATOMIC_RELAXED,
                                        __HIP_MEMORY_SCOPE_AGENT) < (unsigned)(t + 1)) {
        if (++spins > 2000000) dead = 1;
        __builtin_amdgcn_s_sleep(1);
      }
    }
    __syncthreads();
    __threadfence();
    for (int i = tid; i < 512; i += 256) {
      const int rr = i >> 5, c8 = i & 31;
      const float4 v = *(const float4*)(hx1g + rr * NH + c8 * 8);
      *(float4*)(h1p + rr * HROW + c8 * 8) = v;
    }
    __syncthreads();
  }

  // ---- final linear: out[row] = w_lin . h1[row] + b_lin ----
  {
    float part = 0.f;
    #pragma unroll
    for (int e = 0; e < 16; ++e) {
      const int c = u * 16 + e;
      part += __half2float(h1p[r * HROW + c]) * w_lin[c];
    }
    red[r][u] = part;
    __syncthreads();
    if (u == 0 && j == 0) {
      float s = 0.f;
      #pragma unroll
      for (int e = 0; e < 16; ++e) s += red[r][e];
      out[gr * 16 + r] = s + b_lin[0];
    }
  }
}

extern "C" void kernel_launch(void* const* d_in, const int* in_sizes, int n_in,
                              void* d_out, int out_size, void* d_ws, size_t ws_size,
                              hipStream_t stream) {
  (void)in_sizes; (void)n_in; (void)out_size; (void)ws_size;
  const float* x     = (const float*)d_in[0];
  const float* w_ih0 = (const float*)d_in[1];
  const float* w_hh0 = (const float*)d_in[2];
  const float* b_ih0 = (const float*)d_in[3];
  const float* b_hh0 = (const float*)d_in[4];
  const float* w_ih1 = (const float*)d_in[5];
  const float* w_hh1 = (const float*)d_in[6];
  const float* b_ih1 = (const float*)d_in[7];
  const float* b_hh1 = (const float*)d_in[8];
  const float* w_lin = (const float*)d_in[9];
  const float* b_lin = (const float*)d_in[10];

  char* ws = (char*)d_ws;
  unsigned* f0   = (unsigned*)(ws);
  unsigned* f1   = (unsigned*)(ws + 1024);
  __half*   wimg = (__half*)(ws + WIMG_OFF);
  __half*   hx0  = (__half*)(ws + HX0_OFF);
  __half*   hx1  = (__half*)(ws + HX1_OFF);

  hipMemsetAsync(d_ws, 0, FLAGS_BYTES, stream);
  prep_wimg<<<1024, 256, 0, stream>>>(w_ih0, w_hh0, w_ih1, w_hh1, wimg);
  gru_group<<<256, 256, 0, stream>>>(x, b_ih0, b_hh0, b_ih1, b_hh1,
                                     w_lin, b_lin, wimg, hx0, hx1, f0, f1,
                                     (float*)d_out);
}

// Round 4
// 3395.524 us; speedup vs baseline: 26.7895x; 26.7895x over previous
//
#include <hip/hip_runtime.h>
#include <hip/hip_fp16.h>

// GRU 2-layer, B=256 S=1024 F=75 H=256.
// Round 4: R3 structure, but exchange goes through the coherent point (MALL).
//  All exchange accesses (hx publish, flags, gather) use sc0 sc1 = bypass L1+L2,
//  served by memory-side Infinity Cache -> coherent for any block->XCD placement.
//  No threadfence / no L2 writeback (that was R2's 1.16GB WRITE_SIZE).
//  16 groups (16 batch rows) x 16 blocks (16 hidden units), 256 threads (4 waves).
//  Phase p: layer0 step p + layer1 step p-1 (both read gathered h0[p-1]);
//  8 MFMA 16x16 tiles (r,z,nx,nh x 2 layers), 2 per wave; gate math in (row,unit)
//  threads; publish packed (h0,h1) uint; flag+spin+gather; dead-latch bailout.

#define NS 1024
#define NF 75
#define NH 256

// LDS strides in _Float16 elements (16B-aligned rows)
#define W0S 360   // 96(x: 75 pad 96) + 256(h) + 8 pad
#define W1S 520   // 256(h0) + 256(h1) + 8 pad
#define HCS 520   // hcat row: [h0 0..255 | h1 256..511] + 8 pad
#define XSS 104   // 96 + 8 pad

#define W0_HALVES (48 * W0S)                 // 17280
#define W1_HALVES (48 * W1S)                 // 24960
#define IMG_HALVES (W0_HALVES + W1_HALVES)   // 42240

// d_ws layout (bytes)
#define FLAGS_BYTES 4096
#define WIMG_OFF 4096
#define WIMG_BYTES (16 * IMG_HALVES * 2)     // 1,351,680
#define HX_OFF (WIMG_OFF + WIMG_BYTES)
#define HX_UINTS_PAR (16 * 16 * 256)         // 65536 uints (256KB) per parity

typedef _Float16 f16x8 __attribute__((ext_vector_type(8)));
typedef float f32x4 __attribute__((ext_vector_type(4)));
typedef unsigned int u32x4 __attribute__((ext_vector_type(4)));

// ---- coherent (MALL-routed) access helpers: sc0 sc1 = bypass L1 and L2 ----
__device__ __forceinline__ void st_u32_sys(unsigned* p, unsigned v) {
  asm volatile("global_store_dword %0, %1, off sc0 sc1"
               :: "v"(p), "v"(v) : "memory");
}
__device__ __forceinline__ void st_flag_sys(unsigned* p, unsigned v) {
  asm volatile("global_store_dword %0, %1, off sc0 sc1\n\ts_waitcnt vmcnt(0)"
               :: "v"(p), "v"(v) : "memory");
}
__device__ __forceinline__ unsigned ld_flag_sys(const unsigned* p) {
  unsigned v;
  asm volatile("global_load_dword %0, %1, off sc0 sc1\n\ts_waitcnt vmcnt(0)"
               : "=v"(v) : "v"(p) : "memory");
  return v;
}
__device__ __forceinline__ void ld4_sys(const unsigned* p, u32x4& a, u32x4& b,
                                        u32x4& c, u32x4& d) {
  asm volatile(
      "global_load_dwordx4 %0, %4, off sc0 sc1\n\t"
      "global_load_dwordx4 %1, %4, off offset:16 sc0 sc1\n\t"
      "global_load_dwordx4 %2, %4, off offset:32 sc0 sc1\n\t"
      "global_load_dwordx4 %3, %4, off offset:48 sc0 sc1\n\t"
      "s_waitcnt vmcnt(0)"
      : "=&v"(a), "=&v"(b), "=&v"(c), "=&v"(d)
      : "v"(p) : "memory");
}

// Weight image per block j (halves):
//  W0 [48 rows][W0S]: row = gate*16+u (gate 0:r 1:z 2:n), cols 0..74 = w_ih0,
//    75..95 = 0, 96..351 = w_hh0, rest pad.
//  W1 [48 rows][W1S]: cols 0..255 = w_ih1 (input h0), 256..511 = w_hh1.
__global__ void prep_wimg(const float* __restrict__ wih0, const float* __restrict__ whh0,
                          const float* __restrict__ wih1, const float* __restrict__ whh1,
                          _Float16* __restrict__ wimg) {
  const int total = 16 * IMG_HALVES;
  for (int i = blockIdx.x * blockDim.x + threadIdx.x; i < total;
       i += gridDim.x * blockDim.x) {
    const int j = i / IMG_HALVES;
    int rem = i - j * IMG_HALVES;
    float val = 0.f;
    if (rem < W0_HALVES) {
      const int row = rem / W0S, k = rem - row * W0S;
      const int gate = row >> 4, u = row & 15;
      const int grow = gate * NH + j * 16 + u;
      if (k < NF) val = wih0[grow * NF + k];
      else if (k >= 96 && k < 352) val = whh0[grow * NH + (k - 96)];
    } else {
      rem -= W0_HALVES;
      const int row = rem / W1S, k = rem - row * W1S;
      const int gate = row >> 4, u = row & 15;
      const int grow = gate * NH + j * 16 + u;
      if (k < 256) val = wih1[grow * NH + k];
      else if (k < 512) val = whh1[grow * NH + (k - 256)];
    }
    wimg[i] = (_Float16)val;
  }
}

__global__ __launch_bounds__(256, 1) void gru_mfma(
    const float* __restrict__ x,
    const float* __restrict__ b_ih0, const float* __restrict__ b_hh0,
    const float* __restrict__ b_ih1, const float* __restrict__ b_hh1,
    const float* __restrict__ w_lin, const float* __restrict__ b_lin,
    const _Float16* __restrict__ wimg,
    unsigned* __restrict__ hx, unsigned* __restrict__ flags,
    float* __restrict__ out)
{
  const int tid = threadIdx.x;
  const int bid = blockIdx.x;
  // Grouping heuristic (perf-only now; correctness is placement-independent).
  const int gr = (bid & 7) + ((bid >> 7) << 3);
  const int j  = (bid >> 3) & 15;

  __shared__ _Float16 W0s[48 * W0S];
  __shared__ _Float16 W1s[48 * W1S];
  __shared__ _Float16 hcat[16 * HCS];
  __shared__ _Float16 xs[2 * 16 * XSS];
  __shared__ float ctile[8][64][4];
  __shared__ float red[16][17];

  // ---- load weight image ----
  {
    const float4* src = (const float4*)(wimg + (size_t)j * IMG_HALVES);
    float4* d0 = (float4*)W0s;
    for (int i = tid; i < W0_HALVES / 8; i += 256) d0[i] = src[i];
    float4* d1 = (float4*)W1s;
    for (int i = tid; i < W1_HALVES / 8; i += 256) d1[i] = src[W0_HALVES / 8 + i];
  }
  for (int i = tid; i < 16 * HCS; i += 256) hcat[i] = (_Float16)0.f;
  for (int i = tid; i < 2 * 16 * XSS; i += 256) xs[i] = (_Float16)0.f;

  // ---- x-load mapping: 1200 = 16 rows x 75 cols over 256 threads, 5 slots ----
  int xr_[5], xc_[5]; bool xv_[5];
  #pragma unroll
  for (int i = 0; i < 5; ++i) {
    const int idx = i * 256 + tid;
    xv_[i] = idx < 16 * NF;
    xr_[i] = xv_[i] ? idx / NF : 0;
    xc_[i] = xv_[i] ? idx % NF : 0;
  }
  const float* __restrict__ xbase = x + (size_t)(gr * 16) * NS * NF;
  #pragma unroll
  for (int i = 0; i < 5; ++i)
    if (xv_[i]) xs[xr_[i] * XSS + xc_[i]] =
        (_Float16)xbase[(size_t)xr_[i] * NS * NF + xc_[i]];

  const int row = tid >> 4, u = tid & 15, gu = j * 16 + u;

  const float br0 = b_ih0[gu] + b_hh0[gu];
  const float bz0 = b_ih0[NH + gu] + b_hh0[NH + gu];
  const float bnx0 = b_ih0[2 * NH + gu], bnh0 = b_hh0[2 * NH + gu];
  const float br1 = b_ih1[gu] + b_hh1[gu];
  const float bz1 = b_ih1[NH + gu] + b_hh1[NH + gu];
  const float bnx1 = b_ih1[2 * NH + gu], bnh1 = b_hh1[2 * NH + gu];

  const int wid = tid >> 6, lane = tid & 63;
  const int lrow = lane & 15, lko = (lane >> 4) * 8;

  unsigned* __restrict__ flg = flags + gr * 16;
  float h0f = 0.f, h1f = 0.f;
  int dead = 0; int spins = 0;

  __syncthreads();

  for (int p = 0; p <= NS; ++p) {
    const int par = p & 1;

    float xf[5];
    if (p + 1 < NS) {
      #pragma unroll
      for (int i = 0; i < 5; ++i)
        if (xv_[i]) xf[i] = xbase[((size_t)xr_[i] * NS + (p + 1)) * NF + xc_[i]];
    }

    // ---- MFMA: 8 tiles, 2 per wave ----
    {
      const _Float16* __restrict__ xp = xs + par * (16 * XSS) + lrow * XSS + lko;
      const _Float16* __restrict__ hp = hcat + lrow * HCS + lko;
      f32x4 accA = {0.f, 0.f, 0.f, 0.f}, accB = {0.f, 0.f, 0.f, 0.f};
      if (wid == 0) {
        // l0-r (ct0): kb 0..10 ; l1-nx (ct6): kb 0..7
        const _Float16* wb = W0s + lrow * W0S + lko;
        #pragma unroll
        for (int kb = 0; kb < 3; ++kb)
          accA = __builtin_amdgcn_mfma_f32_16x16x32_f16(
              *(const f16x8*)(xp + kb * 32), *(const f16x8*)(wb + kb * 32), accA, 0, 0, 0);
        #pragma unroll
        for (int kb = 3; kb < 11; ++kb)
          accA = __builtin_amdgcn_mfma_f32_16x16x32_f16(
              *(const f16x8*)(hp + kb * 32 - 96), *(const f16x8*)(wb + kb * 32), accA, 0, 0, 0);
        const _Float16* wn = W1s + (32 + lrow) * W1S + lko;
        #pragma unroll
        for (int kb = 0; kb < 8; ++kb)
          accB = __builtin_amdgcn_mfma_f32_16x16x32_f16(
              *(const f16x8*)(hp + kb * 32), *(const f16x8*)(wn + kb * 32), accB, 0, 0, 0);
        *(f32x4*)&ctile[0][lane][0] = accA;
        *(f32x4*)&ctile[6][lane][0] = accB;
      } else if (wid == 1) {
        // l0-z (ct1): kb 0..10 ; l1-nh (ct7): kb 8..15
        const _Float16* wb = W0s + (16 + lrow) * W0S + lko;
        #pragma unroll
        for (int kb = 0; kb < 3; ++kb)
          accA = __builtin_amdgcn_mfma_f32_16x16x32_f16(
              *(const f16x8*)(xp + kb * 32), *(const f16x8*)(wb + kb * 32), accA, 0, 0, 0);
        #pragma unroll
        for (int kb = 3; kb < 11; ++kb)
          accA = __builtin_amdgcn_mfma_f32_16x16x32_f16(
              *(const f16x8*)(hp + kb * 32 - 96), *(const f16x8*)(wb + kb * 32), accA, 0, 0, 0);
        const _Float16* wn = W1s + (32 + lrow) * W1S + lko;
        #pragma unroll
        for (int kb = 8; kb < 16; ++kb)
          accB = __builtin_amdgcn_mfma_f32_16x16x32_f16(
              *(const f16x8*)(hp + kb * 32), *(const f16x8*)(wn + kb * 32), accB, 0, 0, 0);
        *(f32x4*)&ctile[1][lane][0] = accA;
        *(f32x4*)&ctile[7][lane][0] = accB;
      } else if (wid == 2) {
        // l0-nx (ct2): kb 0..2 ; l1-r (ct4): kb 0..15
        const _Float16* wb = W0s + (32 + lrow) * W0S + lko;
        #pragma unroll
        for (int kb = 0; kb < 3; ++kb)
          accA = __builtin_amdgcn_mfma_f32_16x16x32_f16(
              *(const f16x8*)(xp + kb * 32), *(const f16x8*)(wb + kb * 32), accA, 0, 0, 0);
        const _Float16* wn = W1s + lrow * W1S + lko;
        #pragma unroll
        for (int kb = 0; kb < 16; ++kb)
          accB = __builtin_amdgcn_mfma_f32_16x16x32_f16(
              *(const f16x8*)(hp + kb * 32), *(const f16x8*)(wn + kb * 32), accB, 0, 0, 0);
        *(f32x4*)&ctile[2][lane][0] = accA;
        *(f32x4*)&ctile[4][lane][0] = accB;
      } else {
        // l0-nh (ct3): kb 3..10 ; l1-z (ct5): kb 0..15
        const _Float16* wb = W0s + (32 + lrow) * W0S + lko;
        #pragma unroll
        for (int kb = 3; kb < 11; ++kb)
          accA = __builtin_amdgcn_mfma_f32_16x16x32_f16(
              *(const f16x8*)(hp + kb * 32 - 96), *(const f16x8*)(wb + kb * 32), accA, 0, 0, 0);
        const _Float16* wn = W1s + (16 + lrow) * W1S + lko;
        #pragma unroll
        for (int kb = 0; kb < 16; ++kb)
          accB = __builtin_amdgcn_mfma_f32_16x16x32_f16(
              *(const f16x8*)(hp + kb * 32), *(const f16x8*)(wn + kb * 32), accB, 0, 0, 0);
        *(f32x4*)&ctile[3][lane][0] = accA;
        *(f32x4*)&ctile[5][lane][0] = accB;
      }
    }
    __syncthreads();  // S1: ctile ready; all hcat/xs reads done

    // ---- gate math in (row,unit) thread ----
    {
      const int li = ((row >> 2) << 4) | u, rg = row & 3;
      if (p < NS) {
        const float ar = ctile[0][li][rg] + br0;
        const float az = ctile[1][li][rg] + bz0;
        const float nx = ctile[2][li][rg] + bnx0;
        const float nh = ctile[3][li][rg] + bnh0;
        const float r = 1.f / (1.f + __expf(-ar));
        const float z = 1.f / (1.f + __expf(-az));
        const float n = tanhf(nx + r * nh);
        h0f = (1.f - z) * n + z * h0f;
      }
      if (p >= 1) {
        const float ar = ctile[4][li][rg] + br1;
        const float az = ctile[5][li][rg] + bz1;
        const float nx = ctile[6][li][rg] + bnx1;
        const float nh = ctile[7][li][rg] + bnh1;
        const float r = 1.f / (1.f + __expf(-ar));
        const float z = 1.f / (1.f + __expf(-az));
        const float n = tanhf(nx + r * nh);
        h1f = (1.f - z) * n + z * h1f;
      }
    }

    // ---- publish packed (h0,h1) via MALL (coherent) ----
    {
      union { _Float16 h; unsigned short s; } c0, c1;
      c0.h = (_Float16)h0f; c1.h = (_Float16)h1f;
      st_u32_sys(&hx[par * HX_UINTS_PAR + gr * 4096 + row * 256 + gu],
                 (unsigned)c0.s | ((unsigned)c1.s << 16));
    }
    if (p + 1 < NS) {
      #pragma unroll
      for (int i = 0; i < 5; ++i)
        if (xv_[i]) xs[((p + 1) & 1) * (16 * XSS) + xr_[i] * XSS + xc_[i]] =
            (_Float16)xf[i];
    }
    __syncthreads();  // S2: publish stores drained (barrier implies vmcnt(0))
    if (tid == 0) st_flag_sys(&flg[j], (unsigned)(p + 1));
    if (tid < 16) {
      while (!dead && ld_flag_sys(&flg[tid]) < (unsigned)(p + 1)) {
        if (++spins > 1000000) dead = 1;
        __builtin_amdgcn_s_sleep(2);
      }
    }
    __syncthreads();  // S3: all member flags confirmed

    // ---- gather 16KB group state -> hcat ----
    {
      const unsigned* src = hx + par * HX_UINTS_PAR + gr * 4096 + tid * 16;
      u32x4 q0, q1, q2, q3;
      ld4_sys(src, q0, q1, q2, q3);
      const int grow = tid >> 4, gcol = (tid & 15) * 16;
      _Float16* h0d = hcat + grow * HCS + gcol;
      _Float16* h1d = hcat + grow * HCS + 256 + gcol;
      u32x4 qs[4] = {q0, q1, q2, q3};
      #pragma unroll
      for (int k = 0; k < 4; ++k) {
        const u32x4 q = qs[k];
        uint2 lo, hi;
        lo.x = (q.x & 0xffffu) | (q.y << 16);
        lo.y = (q.z & 0xffffu) | (q.w << 16);
        hi.x = (q.x >> 16) | (q.y & 0xffff0000u);
        hi.y = (q.z >> 16) | (q.w & 0xffff0000u);
        *(uint2*)(h0d + k * 4) = lo;
        *(uint2*)(h1d + k * 4) = hi;
      }
    }
    __syncthreads();  // S4: hcat ready for next phase
  }

  // ---- final linear ----
  {
    float part = 0.f;
    #pragma unroll
    for (int e = 0; e < 16; ++e)
      part += (float)hcat[row * HCS + 256 + u * 16 + e] * w_lin[u * 16 + e];
    red[row][u] = part;
    __syncthreads();
    if (j == 0 && tid < 16) {
      float s = 0.f;
      #pragma unroll
      for (int e = 0; e < 16; ++e) s += red[tid][e];
      out[gr * 16 + tid] = s + b_lin[0];
    }
  }
}

extern "C" void kernel_launch(void* const* d_in, const int* in_sizes, int n_in,
                              void* d_out, int out_size, void* d_ws, size_t ws_size,
                              hipStream_t stream) {
  (void)in_sizes; (void)n_in; (void)out_size; (void)ws_size;
  const float* x     = (const float*)d_in[0];
  const float* w_ih0 = (const float*)d_in[1];
  const float* w_hh0 = (const float*)d_in[2];
  const float* b_ih0 = (const float*)d_in[3];
  const float* b_hh0 = (const float*)d_in[4];
  const float* w_ih1 = (const float*)d_in[5];
  const float* w_hh1 = (const float*)d_in[6];
  const float* b_ih1 = (const float*)d_in[7];
  const float* b_hh1 = (const float*)d_in[8];
  const float* w_lin = (const float*)d_in[9];
  const float* b_lin = (const float*)d_in[10];

  char* ws = (char*)d_ws;
  unsigned*  flags = (unsigned*)ws;
  _Float16*  wimg  = (_Float16*)(ws + WIMG_OFF);
  unsigned*  hx    = (unsigned*)(ws + HX_OFF);

  hipMemsetAsync(d_ws, 0, FLAGS_BYTES, stream);
  prep_wimg<<<1024, 256, 0, stream>>>(w_ih0, w_hh0, w_ih1, w_hh1, wimg);
  gru_mfma<<<256, 256, 0, stream>>>(x, b_ih0, b_hh0, b_ih1, b_hh1,
                                    w_lin, b_lin, wimg, hx, flags,
                                    (float*)d_out);
}

// Round 5
// 3237.226 us; speedup vs baseline: 28.0995x; 1.0489x over previous
//
#include <hip/hip_runtime.h>
#include <hip/hip_fp16.h>

// GRU 2-layer, B=256 S=1024 F=75 H=256.
// Round 5: R4 structure (MALL-coherent exchange, verified) +
//  (1) loop-invariant weight fragments held in VGPRs (loaded once from LDS),
//      per-phase LDS reads drop to <=19 b128/wave (A-fragments only, shared);
//  (2) exchange streamlined: fire-and-forget flag store, poll fused with gather
//      (each thread polls the member whose slice it gathers), S3 barrier removed,
//      explicit vmcnt(0) drain before S2.
//  16 groups (16 batch rows) x 16 blocks (16 hidden units), 256 threads (4 waves).
//  Phase p: layer0 step p + layer1 step p-1; 8 MFMA 16x16 tiles, 2 per wave.

#define NS 1024
#define NF 75
#define NH 256

// LDS strides in _Float16 elements (16B-aligned rows)
#define W0S 360   // 96(x: 75 pad 96) + 256(h) + 8 pad
#define W1S 520   // 256(h0) + 256(h1) + 8 pad
#define HCS 520   // hcat row: [h0 0..255 | h1 256..511] + 8 pad
#define XSS 104   // 96 + 8 pad

#define W0_HALVES (48 * W0S)                 // 17280
#define W1_HALVES (48 * W1S)                 // 24960
#define IMG_HALVES (W0_HALVES + W1_HALVES)   // 42240

// d_ws layout (bytes)
#define FLAGS_BYTES 4096
#define WIMG_OFF 4096
#define WIMG_BYTES (16 * IMG_HALVES * 2)     // 1,351,680
#define HX_OFF (WIMG_OFF + WIMG_BYTES)
#define HX_UINTS_PAR (16 * 16 * 256)         // 65536 uints (256KB) per parity

typedef _Float16 f16x8 __attribute__((ext_vector_type(8)));
typedef float f32x4 __attribute__((ext_vector_type(4)));
typedef unsigned int u32x4 __attribute__((ext_vector_type(4)));

// ---- coherent (MALL-routed) access helpers: sc0 sc1 = bypass L1 and L2 ----
__device__ __forceinline__ void st_u32_sys(unsigned* p, unsigned v) {
  asm volatile("global_store_dword %0, %1, off sc0 sc1"
               :: "v"(p), "v"(v) : "memory");
}
__device__ __forceinline__ void st_flag_nw(unsigned* p, unsigned v) {
  // fire-and-forget: data already drained by explicit vmcnt(0) before S2
  asm volatile("global_store_dword %0, %1, off sc0 sc1"
               :: "v"(p), "v"(v) : "memory");
}
__device__ __forceinline__ unsigned ld_flag_sys(const unsigned* p) {
  unsigned v;
  asm volatile("global_load_dword %0, %1, off sc0 sc1\n\ts_waitcnt vmcnt(0)"
               : "=v"(v) : "v"(p) : "memory");
  return v;
}
__device__ __forceinline__ void ld4_sys(const unsigned* p, u32x4& a, u32x4& b,
                                        u32x4& c, u32x4& d) {
  asm volatile(
      "global_load_dwordx4 %0, %4, off sc0 sc1\n\t"
      "global_load_dwordx4 %1, %4, off offset:16 sc0 sc1\n\t"
      "global_load_dwordx4 %2, %4, off offset:32 sc0 sc1\n\t"
      "global_load_dwordx4 %3, %4, off offset:48 sc0 sc1\n\t"
      "s_waitcnt vmcnt(0)"
      : "=&v"(a), "=&v"(b), "=&v"(c), "=&v"(d)
      : "v"(p) : "memory");
}
__device__ __forceinline__ void drain_vm() {
  asm volatile("s_waitcnt vmcnt(0)" ::: "memory");
}

// Weight image per block j (halves):
//  W0 [48 rows][W0S]: row = gate*16+u (gate 0:r 1:z 2:n), cols 0..74 = w_ih0,
//    75..95 = 0, 96..351 = w_hh0, rest pad.
//  W1 [48 rows][W1S]: cols 0..255 = w_ih1 (input h0), 256..511 = w_hh1.
__global__ void prep_wimg(const float* __restrict__ wih0, const float* __restrict__ whh0,
                          const float* __restrict__ wih1, const float* __restrict__ whh1,
                          _Float16* __restrict__ wimg) {
  const int total = 16 * IMG_HALVES;
  for (int i = blockIdx.x * blockDim.x + threadIdx.x; i < total;
       i += gridDim.x * blockDim.x) {
    const int j = i / IMG_HALVES;
    int rem = i - j * IMG_HALVES;
    float val = 0.f;
    if (rem < W0_HALVES) {
      const int row = rem / W0S, k = rem - row * W0S;
      const int gate = row >> 4, u = row & 15;
      const int grow = gate * NH + j * 16 + u;
      if (k < NF) val = wih0[grow * NF + k];
      else if (k >= 96 && k < 352) val = whh0[grow * NH + (k - 96)];
    } else {
      rem -= W0_HALVES;
      const int row = rem / W1S, k = rem - row * W1S;
      const int gate = row >> 4, u = row & 15;
      const int grow = gate * NH + j * 16 + u;
      if (k < 256) val = wih1[grow * NH + k];
      else if (k < 512) val = whh1[grow * NH + (k - 256)];
    }
    wimg[i] = (_Float16)val;
  }
}

__global__ __launch_bounds__(256, 1) void gru_mfma(
    const float* __restrict__ x,
    const float* __restrict__ b_ih0, const float* __restrict__ b_hh0,
    const float* __restrict__ b_ih1, const float* __restrict__ b_hh1,
    const float* __restrict__ w_lin, const float* __restrict__ b_lin,
    const _Float16* __restrict__ wimg,
    unsigned* __restrict__ hx, unsigned* __restrict__ flags,
    float* __restrict__ out)
{
  const int tid = threadIdx.x;
  const int bid = blockIdx.x;
  const int gr = (bid & 7) + ((bid >> 7) << 3);   // perf-only grouping heuristic
  const int j  = (bid >> 3) & 15;

  __shared__ _Float16 W0s[48 * W0S];
  __shared__ _Float16 W1s[48 * W1S];
  __shared__ _Float16 hcat[16 * HCS];
  __shared__ _Float16 xs[2 * 16 * XSS];
  __shared__ float ctile[8][64][4];
  __shared__ float red[16][17];

  // ---- stage weight image into LDS (then hoisted to VGPRs) ----
  {
    const float4* src = (const float4*)(wimg + (size_t)j * IMG_HALVES);
    float4* d0 = (float4*)W0s;
    for (int i = tid; i < W0_HALVES / 8; i += 256) d0[i] = src[i];
    float4* d1 = (float4*)W1s;
    for (int i = tid; i < W1_HALVES / 8; i += 256) d1[i] = src[W0_HALVES / 8 + i];
  }
  for (int i = tid; i < 16 * HCS; i += 256) hcat[i] = (_Float16)0.f;
  for (int i = tid; i < 2 * 16 * XSS; i += 256) xs[i] = (_Float16)0.f;

  // ---- x-load mapping: 1200 = 16 rows x 75 cols over 256 threads, 5 slots ----
  int xr_[5], xc_[5]; bool xv_[5];
  #pragma unroll
  for (int i = 0; i < 5; ++i) {
    const int idx = i * 256 + tid;
    xv_[i] = idx < 16 * NF;
    xr_[i] = xv_[i] ? idx / NF : 0;
    xc_[i] = xv_[i] ? idx % NF : 0;
  }
  const float* __restrict__ xbase = x + (size_t)(gr * 16) * NS * NF;
  #pragma unroll
  for (int i = 0; i < 5; ++i)
    if (xv_[i]) xs[xr_[i] * XSS + xc_[i]] =
        (_Float16)xbase[(size_t)xr_[i] * NS * NF + xc_[i]];

  const int row = tid >> 4, u = tid & 15, gu = j * 16 + u;

  const float br0 = b_ih0[gu] + b_hh0[gu];
  const float bz0 = b_ih0[NH + gu] + b_hh0[NH + gu];
  const float bnx0 = b_ih0[2 * NH + gu], bnh0 = b_hh0[2 * NH + gu];
  const float br1 = b_ih1[gu] + b_hh1[gu];
  const float bz1 = b_ih1[NH + gu] + b_hh1[NH + gu];
  const float bnx1 = b_ih1[2 * NH + gu], bnh1 = b_hh1[2 * NH + gu];

  const int wid = tid >> 6, lane = tid & 63;
  const int lrow = lane & 15, lko = (lane >> 4) * 8;

  unsigned* __restrict__ flg = flags + gr * 16;
  float h0f = 0.f, h1f = 0.f;
  int dead = 0; int spins = 0;

  __syncthreads();   // W0s/W1s + hcat/xs(t=0) visible

  // ---- hoist loop-invariant B-fragments to VGPRs ----
  f16x8 Bw[11], Bn[16];
  if (wid == 0) {            // L0-r (ct0) + L1-nx (ct6)
    const _Float16* wb = W0s + lrow * W0S + lko;
    #pragma unroll
    for (int i = 0; i < 11; ++i) Bw[i] = *(const f16x8*)(wb + i * 32);
    const _Float16* wn = W1s + (32 + lrow) * W1S + lko;
    #pragma unroll
    for (int i = 0; i < 8; ++i) Bn[i] = *(const f16x8*)(wn + i * 32);
  } else if (wid == 1) {     // L0-z (ct1) + L1-nh (ct7)
    const _Float16* wb = W0s + (16 + lrow) * W0S + lko;
    #pragma unroll
    for (int i = 0; i < 11; ++i) Bw[i] = *(const f16x8*)(wb + i * 32);
    const _Float16* wn = W1s + (32 + lrow) * W1S + lko;
    #pragma unroll
    for (int i = 0; i < 8; ++i) Bn[i] = *(const f16x8*)(wn + (8 + i) * 32);
  } else if (wid == 2) {     // L0-nx (ct2) + L1-r (ct4)
    const _Float16* wb = W0s + (32 + lrow) * W0S + lko;
    #pragma unroll
    for (int i = 0; i < 3; ++i) Bw[i] = *(const f16x8*)(wb + i * 32);
    const _Float16* wn = W1s + lrow * W1S + lko;
    #pragma unroll
    for (int i = 0; i < 16; ++i) Bn[i] = *(const f16x8*)(wn + i * 32);
  } else {                   // L0-nh (ct3) + L1-z (ct5)
    const _Float16* wb = W0s + (32 + lrow) * W0S + lko;
    #pragma unroll
    for (int i = 0; i < 8; ++i) Bw[i] = *(const f16x8*)(wb + (3 + i) * 32);
    const _Float16* wn = W1s + (16 + lrow) * W1S + lko;
    #pragma unroll
    for (int i = 0; i < 16; ++i) Bn[i] = *(const f16x8*)(wn + i * 32);
  }

  for (int p = 0; p <= NS; ++p) {
    const int par = p & 1;

    float xf[5];
    if (p + 1 < NS) {
      #pragma unroll
      for (int i = 0; i < 5; ++i)
        if (xv_[i]) xf[i] = xbase[((size_t)xr_[i] * NS + (p + 1)) * NF + xc_[i]];
    }

    // ---- A-fragments from LDS (shared within wave's two tile chains) ----
    {
      const _Float16* __restrict__ xp = xs + par * (16 * XSS) + lrow * XSS + lko;
      const _Float16* __restrict__ hp = hcat + lrow * HCS + lko;
      f16x8 xa0, xa1, xa2;
      if (wid != 3) {
        xa0 = *(const f16x8*)(xp);
        xa1 = *(const f16x8*)(xp + 32);
        xa2 = *(const f16x8*)(xp + 64);
      }
      f16x8 hfr[16];
      #pragma unroll
      for (int kb = 0; kb < 8; ++kb) hfr[kb] = *(const f16x8*)(hp + kb * 32);
      if (wid != 0) {
        #pragma unroll
        for (int kb = 8; kb < 16; ++kb) hfr[kb] = *(const f16x8*)(hp + kb * 32);
      }

      f32x4 accA = {0.f, 0.f, 0.f, 0.f}, accB = {0.f, 0.f, 0.f, 0.f};
      if (wid == 0) {
        accA = __builtin_amdgcn_mfma_f32_16x16x32_f16(xa0, Bw[0], accA, 0, 0, 0);
        accA = __builtin_amdgcn_mfma_f32_16x16x32_f16(xa1, Bw[1], accA, 0, 0, 0);
        accA = __builtin_amdgcn_mfma_f32_16x16x32_f16(xa2, Bw[2], accA, 0, 0, 0);
        #pragma unroll
        for (int kb = 0; kb < 8; ++kb)
          accA = __builtin_amdgcn_mfma_f32_16x16x32_f16(hfr[kb], Bw[3 + kb], accA, 0, 0, 0);
        #pragma unroll
        for (int kb = 0; kb < 8; ++kb)
          accB = __builtin_amdgcn_mfma_f32_16x16x32_f16(hfr[kb], Bn[kb], accB, 0, 0, 0);
        *(f32x4*)&ctile[0][lane][0] = accA;
        *(f32x4*)&ctile[6][lane][0] = accB;
      } else if (wid == 1) {
        accA = __builtin_amdgcn_mfma_f32_16x16x32_f16(xa0, Bw[0], accA, 0, 0, 0);
        accA = __builtin_amdgcn_mfma_f32_16x16x32_f16(xa1, Bw[1], accA, 0, 0, 0);
        accA = __builtin_amdgcn_mfma_f32_16x16x32_f16(xa2, Bw[2], accA, 0, 0, 0);
        #pragma unroll
        for (int kb = 0; kb < 8; ++kb)
          accA = __builtin_amdgcn_mfma_f32_16x16x32_f16(hfr[kb], Bw[3 + kb], accA, 0, 0, 0);
        #pragma unroll
        for (int kb = 0; kb < 8; ++kb)
          accB = __builtin_amdgcn_mfma_f32_16x16x32_f16(hfr[8 + kb], Bn[kb], accB, 0, 0, 0);
        *(f32x4*)&ctile[1][lane][0] = accA;
        *(f32x4*)&ctile[7][lane][0] = accB;
      } else if (wid == 2) {
        accA = __builtin_amdgcn_mfma_f32_16x16x32_f16(xa0, Bw[0], accA, 0, 0, 0);
        accA = __builtin_amdgcn_mfma_f32_16x16x32_f16(xa1, Bw[1], accA, 0, 0, 0);
        accA = __builtin_amdgcn_mfma_f32_16x16x32_f16(xa2, Bw[2], accA, 0, 0, 0);
        #pragma unroll
        for (int kb = 0; kb < 16; ++kb)
          accB = __builtin_amdgcn_mfma_f32_16x16x32_f16(hfr[kb], Bn[kb], accB, 0, 0, 0);
        *(f32x4*)&ctile[2][lane][0] = accA;
        *(f32x4*)&ctile[4][lane][0] = accB;
      } else {
        #pragma unroll
        for (int kb = 0; kb < 8; ++kb)
          accA = __builtin_amdgcn_mfma_f32_16x16x32_f16(hfr[kb], Bw[kb], accA, 0, 0, 0);
        #pragma unroll
        for (int kb = 0; kb < 16; ++kb)
          accB = __builtin_amdgcn_mfma_f32_16x16x32_f16(hfr[kb], Bn[kb], accB, 0, 0, 0);
        *(f32x4*)&ctile[3][lane][0] = accA;
        *(f32x4*)&ctile[5][lane][0] = accB;
      }
    }
    __syncthreads();  // S1: ctile ready; all hcat/xs reads done

    // ---- gate math in (row,unit) thread ----
    {
      const int li = ((row >> 2) << 4) | u, rg = row & 3;
      if (p < NS) {
        const float ar = ctile[0][li][rg] + br0;
        const float az = ctile[1][li][rg] + bz0;
        const float nx = ctile[2][li][rg] + bnx0;
        const float nh = ctile[3][li][rg] + bnh0;
        const float r = 1.f / (1.f + __expf(-ar));
        const float z = 1.f / (1.f + __expf(-az));
        const float n = tanhf(nx + r * nh);
        h0f = (1.f - z) * n + z * h0f;
      }
      if (p >= 1) {
        const float ar = ctile[4][li][rg] + br1;
        const float az = ctile[5][li][rg] + bz1;
        const float nx = ctile[6][li][rg] + bnx1;
        const float nh = ctile[7][li][rg] + bnh1;
        const float r = 1.f / (1.f + __expf(-ar));
        const float z = 1.f / (1.f + __expf(-az));
        const float n = tanhf(nx + r * nh);
        h1f = (1.f - z) * n + z * h1f;
      }
    }

    // ---- publish packed (h0,h1) via MALL (coherent) ----
    {
      union { _Float16 h; unsigned short s; } c0, c1;
      c0.h = (_Float16)h0f; c1.h = (_Float16)h1f;
      st_u32_sys(&hx[par * HX_UINTS_PAR + gr * 4096 + row * 256 + gu],
                 (unsigned)c0.s | ((unsigned)c1.s << 16));
    }
    if (p + 1 < NS) {
      #pragma unroll
      for (int i = 0; i < 5; ++i)
        if (xv_[i]) xs[((p + 1) & 1) * (16 * XSS) + xr_[i] * XSS + xc_[i]] =
            (_Float16)xf[i];
    }
    drain_vm();       // publish stores at MALL before anyone's flag can be seen
    __syncthreads();  // S2: whole block drained
    if (tid == 0) st_flag_nw(&flg[j], (unsigned)(p + 1));

    // ---- fused poll+gather: thread handles member mj = tid&15, row rr = tid>>4 ----
    {
      const int mj = tid & 15, rr = tid >> 4;
      while (!dead && ld_flag_sys(&flg[mj]) < (unsigned)(p + 1)) {
        if (++spins > 1000000) dead = 1;
        __builtin_amdgcn_s_sleep(2);
      }
      const unsigned* src = hx + par * HX_UINTS_PAR + gr * 4096 + rr * 256 + mj * 16;
      u32x4 q0, q1, q2, q3;
      ld4_sys(src, q0, q1, q2, q3);
      _Float16* h0d = hcat + rr * HCS + mj * 16;
      _Float16* h1d = h0d + 256;
      u32x4 qs[4] = {q0, q1, q2, q3};
      #pragma unroll
      for (int k = 0; k < 4; ++k) {
        const u32x4 q = qs[k];
        uint2 lo, hi;
        lo.x = (q.x & 0xffffu) | (q.y << 16);
        lo.y = (q.z & 0xffffu) | (q.w << 16);
        hi.x = (q.x >> 16) | (q.y & 0xffff0000u);
        hi.y = (q.z >> 16) | (q.w & 0xffff0000u);
        *(uint2*)(h0d + k * 4) = lo;
        *(uint2*)(h1d + k * 4) = hi;
      }
    }
    __syncthreads();  // S4: hcat ready for next phase
  }

  // ---- final linear ----
  {
    float part = 0.f;
    #pragma unroll
    for (int e = 0; e < 16; ++e)
      part += (float)hcat[row * HCS + 256 + u * 16 + e] * w_lin[u * 16 + e];
    red[row][u] = part;
    __syncthreads();
    if (j == 0 && tid < 16) {
      float s = 0.f;
      #pragma unroll
      for (int e = 0; e < 16; ++e) s += red[tid][e];
      out[gr * 16 + tid] = s + b_lin[0];
    }
  }
}

extern "C" void kernel_launch(void* const* d_in, const int* in_sizes, int n_in,
                              void* d_out, int out_size, void* d_ws, size_t ws_size,
                              hipStream_t stream) {
  (void)in_sizes; (void)n_in; (void)out_size; (void)ws_size;
  const float* x     = (const float*)d_in[0];
  const float* w_ih0 = (const float*)d_in[1];
  const float* w_hh0 = (const float*)d_in[2];
  const float* b_ih0 = (const float*)d_in[3];
  const float* b_hh0 = (const float*)d_in[4];
  const float* w_ih1 = (const float*)d_in[5];
  const float* w_hh1 = (const float*)d_in[6];
  const float* b_ih1 = (const float*)d_in[7];
  const float* b_hh1 = (const float*)d_in[8];
  const float* w_lin = (const float*)d_in[9];
  const float* b_lin = (const float*)d_in[10];

  char* ws = (char*)d_ws;
  unsigned*  flags = (unsigned*)ws;
  _Float16*  wimg  = (_Float16*)(ws + WIMG_OFF);
  unsigned*  hx    = (unsigned*)(ws + HX_OFF);

  hipMemsetAsync(d_ws, 0, FLAGS_BYTES, stream);
  prep_wimg<<<1024, 256, 0, stream>>>(w_ih0, w_hh0, w_ih1, w_hh1, wimg);
  gru_mfma<<<256, 256, 0, stream>>>(x, b_ih0, b_hh0, b_ih1, b_hh1,
                                    w_lin, b_lin, wimg, hx, flags,
                                    (float*)d_out);
}

// Round 7
// 3205.774 us; speedup vs baseline: 28.3752x; 1.0098x over previous
//
#include <hip/hip_runtime.h>
#include <hip/hip_fp16.h>

// GRU 2-layer, B=256 S=1024 F=75 H=256.
// Round 7: R6 minus the unproven sc0-only fast path (prime suspect for R6's
//  absmax failure). Exchange is the R4/R5-proven MALL route (sc0 sc1) only.
//  Kept from R6: (1) asm-pinned weight fragments in VGPRs (no remat),
//  (2) phase reorder: L0 MFMA -> h0 gate+publish -> L1 MFMA -> h1 gate+publish
//      -> drain -> flag -> fused poll+gather (publish commits under compute),
//  (3) hx split into u16 h0/h1 arrays (no pack/unpack, 32B-copy gather).

#define NS 1024
#define NF 75
#define NH 256

#define W0S 360   // 96(x pad) + 256(h) + 8 pad  halves
#define W1S 520   // 256(h0) + 256(h1) + 8 pad
#define HCS 520   // hcat row: [h0 0..255 | h1 256..511] + 8 pad
#define XSS 104   // 96 + 8 pad

#define W0_HALVES (48 * W0S)                 // 17280
#define W1_HALVES (48 * W1S)                 // 24960
#define IMG_HALVES (W0_HALVES + W1_HALVES)   // 42240

// d_ws layout (bytes)
#define FLAGS_OFF 0                          // 16gr x 16 u32
#define HDR_BYTES 4096
#define WIMG_OFF 4096
#define WIMG_BYTES (16 * IMG_HALVES * 2)     // 1,351,680
#define HX0_OFF (WIMG_OFF + WIMG_BYTES)
#define HX_ELEMS_PAR (16 * 16 * 256)         // u16 per parity = 65536
#define HX_BYTES (2 * HX_ELEMS_PAR * 2)      // 262,144
#define HX1_OFF (HX0_OFF + HX_BYTES)

typedef _Float16 f16x8 __attribute__((ext_vector_type(8)));
typedef float f32x4 __attribute__((ext_vector_type(4)));
typedef unsigned int u32x4 __attribute__((ext_vector_type(4)));

#define PINV(x) asm volatile("" : "+v"(x))

// ---- MALL-routed (coherent) access helpers: sc0 sc1 = bypass L1 and L2 ----
__device__ __forceinline__ void st_h16_sys(unsigned short* p, unsigned v) {
  asm volatile("global_store_short %0, %1, off sc0 sc1" :: "v"(p), "v"(v) : "memory");
}
__device__ __forceinline__ void st_u32_sys(unsigned* p, unsigned v) {
  asm volatile("global_store_dword %0, %1, off sc0 sc1" :: "v"(p), "v"(v) : "memory");
}
__device__ __forceinline__ unsigned ld_u32_sys(const unsigned* p) {
  unsigned v;
  asm volatile("global_load_dword %0, %1, off sc0 sc1\n\ts_waitcnt vmcnt(0)"
               : "=v"(v) : "v"(p) : "memory");
  return v;
}
__device__ __forceinline__ void ld_2x32B_sys(const unsigned* p0, const unsigned* p1,
                                             u32x4& a0, u32x4& a1, u32x4& b0, u32x4& b1) {
  asm volatile(
      "global_load_dwordx4 %0, %4, off sc0 sc1\n\t"
      "global_load_dwordx4 %1, %4, off offset:16 sc0 sc1\n\t"
      "global_load_dwordx4 %2, %5, off sc0 sc1\n\t"
      "global_load_dwordx4 %3, %5, off offset:16 sc0 sc1\n\t"
      "s_waitcnt vmcnt(0)"
      : "=&v"(a0), "=&v"(a1), "=&v"(b0), "=&v"(b1)
      : "v"(p0), "v"(p1) : "memory");
}
__device__ __forceinline__ void drain_vm() {
  asm volatile("s_waitcnt vmcnt(0)" ::: "memory");
}

// Weight image per block j (halves):
//  W0 [48 rows][W0S]: row = gate*16+u (gate 0:r 1:z 2:n), cols 0..74 = w_ih0,
//    75..95 = 0, 96..351 = w_hh0, rest pad.
//  W1 [48 rows][W1S]: cols 0..255 = w_ih1 (input h0), 256..511 = w_hh1.
__global__ void prep_wimg(const float* __restrict__ wih0, const float* __restrict__ whh0,
                          const float* __restrict__ wih1, const float* __restrict__ whh1,
                          _Float16* __restrict__ wimg) {
  const int total = 16 * IMG_HALVES;
  for (int i = blockIdx.x * blockDim.x + threadIdx.x; i < total;
       i += gridDim.x * blockDim.x) {
    const int j = i / IMG_HALVES;
    int rem = i - j * IMG_HALVES;
    float val = 0.f;
    if (rem < W0_HALVES) {
      const int row = rem / W0S, k = rem - row * W0S;
      const int gate = row >> 4, u = row & 15;
      const int grow = gate * NH + j * 16 + u;
      if (k < NF) val = wih0[grow * NF + k];
      else if (k >= 96 && k < 352) val = whh0[grow * NH + (k - 96)];
    } else {
      rem -= W0_HALVES;
      const int row = rem / W1S, k = rem - row * W1S;
      const int gate = row >> 4, u = row & 15;
      const int grow = gate * NH + j * 16 + u;
      if (k < 256) val = wih1[grow * NH + k];
      else if (k < 512) val = whh1[grow * NH + (k - 256)];
    }
    wimg[i] = (_Float16)val;
  }
}

__global__ __launch_bounds__(256, 1) void gru_mfma(
    const float* __restrict__ x,
    const float* __restrict__ b_ih0, const float* __restrict__ b_hh0,
    const float* __restrict__ b_ih1, const float* __restrict__ b_hh1,
    const float* __restrict__ w_lin, const float* __restrict__ b_lin,
    const _Float16* __restrict__ wimg,
    unsigned short* __restrict__ hx0, unsigned short* __restrict__ hx1,
    unsigned* __restrict__ flags,
    float* __restrict__ out)
{
  const int tid = threadIdx.x;
  const int bid = blockIdx.x;
  const int gr = (bid & 7) + ((bid >> 7) << 3);   // grouping heuristic (perf-only)
  const int j  = (bid >> 3) & 15;

  __shared__ _Float16 W0s[48 * W0S];
  __shared__ _Float16 W1s[48 * W1S];
  __shared__ _Float16 hcat[16 * HCS];
  __shared__ _Float16 xs[2 * 16 * XSS];
  __shared__ float ctile[8][64][4];
  __shared__ float red[16][17];

  int dead = 0, spins = 0;

  // ---- stage weight image into LDS ----
  {
    const float4* src = (const float4*)(wimg + (size_t)j * IMG_HALVES);
    float4* d0 = (float4*)W0s;
    for (int i = tid; i < W0_HALVES / 8; i += 256) d0[i] = src[i];
    float4* d1 = (float4*)W1s;
    for (int i = tid; i < W1_HALVES / 8; i += 256) d1[i] = src[W0_HALVES / 8 + i];
  }
  for (int i = tid; i < 16 * HCS; i += 256) hcat[i] = (_Float16)0.f;
  for (int i = tid; i < 2 * 16 * XSS; i += 256) xs[i] = (_Float16)0.f;

  // ---- x-load mapping: 1200 = 16 rows x 75 cols over 256 threads, 5 slots ----
  int xr_[5], xc_[5]; bool xv_[5];
  #pragma unroll
  for (int i = 0; i < 5; ++i) {
    const int idx = i * 256 + tid;
    xv_[i] = idx < 16 * NF;
    xr_[i] = xv_[i] ? idx / NF : 0;
    xc_[i] = xv_[i] ? idx % NF : 0;
  }
  const float* __restrict__ xbase = x + (size_t)(gr * 16) * NS * NF;
  #pragma unroll
  for (int i = 0; i < 5; ++i)
    if (xv_[i]) xs[xr_[i] * XSS + xc_[i]] =
        (_Float16)xbase[(size_t)xr_[i] * NS * NF + xc_[i]];

  const int row = tid >> 4, u = tid & 15, gu = j * 16 + u;

  const float br0 = b_ih0[gu] + b_hh0[gu];
  const float bz0 = b_ih0[NH + gu] + b_hh0[NH + gu];
  const float bnx0 = b_ih0[2 * NH + gu], bnh0 = b_hh0[2 * NH + gu];
  const float br1 = b_ih1[gu] + b_hh1[gu];
  const float bz1 = b_ih1[NH + gu] + b_hh1[NH + gu];
  const float bnx1 = b_ih1[2 * NH + gu], bnh1 = b_hh1[2 * NH + gu];

  const int wid = tid >> 6, lane = tid & 63;
  const int lrow = lane & 15, lko = (lane >> 4) * 8;

  unsigned* __restrict__ flg = flags + gr * 16;
  float h0f = 0.f, h1f = 0.f;

  __syncthreads();   // W0s/W1s + hcat/xs(t=0) visible

  // ---- hoist loop-invariant B-fragments to VGPRs (pinned: no remat) ----
  f16x8 Bw[11], Bn[16];
  if (wid == 0) {            // L0-r (ct0) + L1-nx (ct6)
    const _Float16* wb = W0s + lrow * W0S + lko;
    #pragma unroll
    for (int i = 0; i < 11; ++i) { Bw[i] = *(const f16x8*)(wb + i * 32); PINV(Bw[i]); }
    const _Float16* wn = W1s + (32 + lrow) * W1S + lko;
    #pragma unroll
    for (int i = 0; i < 8; ++i) { Bn[i] = *(const f16x8*)(wn + i * 32); PINV(Bn[i]); }
  } else if (wid == 1) {     // L0-z (ct1) + L1-nh (ct7)
    const _Float16* wb = W0s + (16 + lrow) * W0S + lko;
    #pragma unroll
    for (int i = 0; i < 11; ++i) { Bw[i] = *(const f16x8*)(wb + i * 32); PINV(Bw[i]); }
    const _Float16* wn = W1s + (32 + lrow) * W1S + lko;
    #pragma unroll
    for (int i = 0; i < 8; ++i) { Bn[i] = *(const f16x8*)(wn + (8 + i) * 32); PINV(Bn[i]); }
  } else if (wid == 2) {     // L0-nx (ct2) + L1-r (ct4)
    const _Float16* wb = W0s + (32 + lrow) * W0S + lko;
    #pragma unroll
    for (int i = 0; i < 3; ++i) { Bw[i] = *(const f16x8*)(wb + i * 32); PINV(Bw[i]); }
    const _Float16* wn = W1s + lrow * W1S + lko;
    #pragma unroll
    for (int i = 0; i < 16; ++i) { Bn[i] = *(const f16x8*)(wn + i * 32); PINV(Bn[i]); }
  } else {                   // L0-nh (ct3) + L1-z (ct5)
    const _Float16* wb = W0s + (32 + lrow) * W0S + lko;
    #pragma unroll
    for (int i = 0; i < 8; ++i) { Bw[i] = *(const f16x8*)(wb + (3 + i) * 32); PINV(Bw[i]); }
    const _Float16* wn = W1s + (16 + lrow) * W1S + lko;
    #pragma unroll
    for (int i = 0; i < 16; ++i) { Bn[i] = *(const f16x8*)(wn + i * 32); PINV(Bn[i]); }
  }

  for (int p = 0; p <= NS; ++p) {
    const int par = p & 1;

    // 1. next-x prefetch (global, overlaps everything below)
    float xf[5];
    if (p + 1 < NS) {
      #pragma unroll
      for (int i = 0; i < 5; ++i)
        if (xv_[i]) xf[i] = xbase[((size_t)xr_[i] * NS + (p + 1)) * NF + xc_[i]];
    }

    // 2. A-fragments from LDS
    const _Float16* __restrict__ xp = xs + par * (16 * XSS) + lrow * XSS + lko;
    const _Float16* __restrict__ hp = hcat + lrow * HCS + lko;
    f16x8 xa0{}, xa1{}, xa2{};
    if (wid != 3) {
      xa0 = *(const f16x8*)(xp);
      xa1 = *(const f16x8*)(xp + 32);
      xa2 = *(const f16x8*)(xp + 64);
    }
    f16x8 hfr[16];
    #pragma unroll
    for (int kb = 0; kb < 8; ++kb) hfr[kb] = *(const f16x8*)(hp + kb * 32);
    if (wid != 0) {
      #pragma unroll
      for (int kb = 8; kb < 16; ++kb) hfr[kb] = *(const f16x8*)(hp + kb * 32);
    }

    // 3. L0 MFMA tiles (ct0..3)
    {
      f32x4 accA = {0.f, 0.f, 0.f, 0.f};
      if (wid <= 1) {
        accA = __builtin_amdgcn_mfma_f32_16x16x32_f16(xa0, Bw[0], accA, 0, 0, 0);
        accA = __builtin_amdgcn_mfma_f32_16x16x32_f16(xa1, Bw[1], accA, 0, 0, 0);
        accA = __builtin_amdgcn_mfma_f32_16x16x32_f16(xa2, Bw[2], accA, 0, 0, 0);
        #pragma unroll
        for (int kb = 0; kb < 8; ++kb)
          accA = __builtin_amdgcn_mfma_f32_16x16x32_f16(hfr[kb], Bw[3 + kb], accA, 0, 0, 0);
        *(f32x4*)&ctile[wid][lane][0] = accA;
      } else if (wid == 2) {
        accA = __builtin_amdgcn_mfma_f32_16x16x32_f16(xa0, Bw[0], accA, 0, 0, 0);
        accA = __builtin_amdgcn_mfma_f32_16x16x32_f16(xa1, Bw[1], accA, 0, 0, 0);
        accA = __builtin_amdgcn_mfma_f32_16x16x32_f16(xa2, Bw[2], accA, 0, 0, 0);
        *(f32x4*)&ctile[2][lane][0] = accA;
      } else {
        #pragma unroll
        for (int kb = 0; kb < 8; ++kb)
          accA = __builtin_amdgcn_mfma_f32_16x16x32_f16(hfr[kb], Bw[kb], accA, 0, 0, 0);
        *(f32x4*)&ctile[3][lane][0] = accA;
      }
    }
    __syncthreads();  // S1: ct0..3 ready

    // 4. h0 gate + EARLY publish (stores commit under L1 MFMA)
    const int li = ((row >> 2) << 4) | u, rg = row & 3;
    if (p < NS) {
      const float ar = ctile[0][li][rg] + br0;
      const float az = ctile[1][li][rg] + bz0;
      const float nx = ctile[2][li][rg] + bnx0;
      const float nh = ctile[3][li][rg] + bnh0;
      const float r = 1.f / (1.f + __expf(-ar));
      const float z = 1.f / (1.f + __expf(-az));
      const float n = tanhf(nx + r * nh);
      h0f = (1.f - z) * n + z * h0f;
    }
    {
      union { _Float16 h; unsigned short s; } c; c.h = (_Float16)h0f;
      st_h16_sys(hx0 + par * HX_ELEMS_PAR + gr * 4096 + row * 256 + gu, c.s);
    }

    // 5. L1 MFMA tiles (ct4..7) — register/LDS only, publish commits underneath
    {
      f32x4 accB = {0.f, 0.f, 0.f, 0.f};
      if (wid == 0) {
        #pragma unroll
        for (int kb = 0; kb < 8; ++kb)
          accB = __builtin_amdgcn_mfma_f32_16x16x32_f16(hfr[kb], Bn[kb], accB, 0, 0, 0);
        *(f32x4*)&ctile[6][lane][0] = accB;
      } else if (wid == 1) {
        #pragma unroll
        for (int kb = 0; kb < 8; ++kb)
          accB = __builtin_amdgcn_mfma_f32_16x16x32_f16(hfr[8 + kb], Bn[kb], accB, 0, 0, 0);
        *(f32x4*)&ctile[7][lane][0] = accB;
      } else {
        #pragma unroll
        for (int kb = 0; kb < 16; ++kb)
          accB = __builtin_amdgcn_mfma_f32_16x16x32_f16(hfr[kb], Bn[kb], accB, 0, 0, 0);
        *(f32x4*)&ctile[2 + wid][lane][0] = accB;   // wid2->4, wid3->5
      }
    }
    __syncthreads();  // S2: ct4..7 ready

    // 6. h1 gate + publish
    if (p >= 1) {
      const float ar = ctile[4][li][rg] + br1;
      const float az = ctile[5][li][rg] + bz1;
      const float nx = ctile[6][li][rg] + bnx1;
      const float nh = ctile[7][li][rg] + bnh1;
      const float r = 1.f / (1.f + __expf(-ar));
      const float z = 1.f / (1.f + __expf(-az));
      const float n = tanhf(nx + r * nh);
      h1f = (1.f - z) * n + z * h1f;
    }
    {
      union { _Float16 h; unsigned short s; } c; c.h = (_Float16)h1f;
      st_h16_sys(hx1 + par * HX_ELEMS_PAR + gr * 4096 + row * 256 + gu, c.s);
    }

    // 7. stage x[t+1]
    if (p + 1 < NS) {
      #pragma unroll
      for (int i = 0; i < 5; ++i)
        if (xv_[i]) xs[((p + 1) & 1) * (16 * XSS) + xr_[i] * XSS + xc_[i]] =
            (_Float16)xf[i];
    }

    // 8. drain + flag + fused poll/gather (MALL path, R4/R5-proven)
    drain_vm();
    __syncthreads();  // S3: all publish stores committed block-wide
    if (tid == 0) st_u32_sys(&flg[j], (unsigned)(p + 1));
    {
      const int mj = tid & 15, rr = tid >> 4;
      while (!dead && ld_u32_sys(&flg[mj]) < (unsigned)(p + 1)) {
        if (++spins > 1000000) dead = 1;
        __builtin_amdgcn_s_sleep(1);
      }
      const int off = par * HX_ELEMS_PAR + gr * 4096 + rr * 256 + mj * 16;
      u32x4 a0, a1, b0, b1;
      ld_2x32B_sys((const unsigned*)(hx0 + off), (const unsigned*)(hx1 + off),
                   a0, a1, b0, b1);
      _Float16* h0d = hcat + rr * HCS + mj * 16;
      *(u32x4*)h0d = a0;       *(u32x4*)(h0d + 8) = a1;
      _Float16* h1d = h0d + 256;
      *(u32x4*)h1d = b0;       *(u32x4*)(h1d + 8) = b1;
    }
    __syncthreads();  // S4: hcat ready for next phase
  }

  // ---- final linear ----
  {
    float part = 0.f;
    #pragma unroll
    for (int e = 0; e < 16; ++e)
      part += (float)hcat[row * HCS + 256 + u * 16 + e] * w_lin[u * 16 + e];
    red[row][u] = part;
    __syncthreads();
    if (j == 0 && tid < 16) {
      float s = 0.f;
      #pragma unroll
      for (int e = 0; e < 16; ++e) s += red[tid][e];
      out[gr * 16 + tid] = s + b_lin[0];
    }
  }
}

extern "C" void kernel_launch(void* const* d_in, const int* in_sizes, int n_in,
                              void* d_out, int out_size, void* d_ws, size_t ws_size,
                              hipStream_t stream) {
  (void)in_sizes; (void)n_in; (void)out_size; (void)ws_size;
  const float* x     = (const float*)d_in[0];
  const float* w_ih0 = (const float*)d_in[1];
  const float* w_hh0 = (const float*)d_in[2];
  const float* b_ih0 = (const float*)d_in[3];
  const float* b_hh0 = (const float*)d_in[4];
  const float* w_ih1 = (const float*)d_in[5];
  const float* w_hh1 = (const float*)d_in[6];
  const float* b_ih1 = (const float*)d_in[7];
  const float* b_hh1 = (const float*)d_in[8];
  const float* w_lin = (const float*)d_in[9];
  const float* b_lin = (const float*)d_in[10];

  char* ws = (char*)d_ws;
  unsigned*       flags = (unsigned*)(ws + FLAGS_OFF);
  _Float16*       wimg  = (_Float16*)(ws + WIMG_OFF);
  unsigned short* hx0   = (unsigned short*)(ws + HX0_OFF);
  unsigned short* hx1   = (unsigned short*)(ws + HX1_OFF);

  hipMemsetAsync(d_ws, 0, HDR_BYTES, stream);
  prep_wimg<<<1024, 256, 0, stream>>>(w_ih0, w_hh0, w_ih1, w_hh1, wimg);
  gru_mfma<<<256, 256, 0, stream>>>(x, b_ih0, b_hh0, b_ih1, b_hh1,
                                    w_lin, b_lin, wimg, hx0, hx1, flags,
                                    (float*)d_out);
}

// Round 8
// 2909.689 us; speedup vs baseline: 31.2626x; 1.1018x over previous
//
#include <hip/hip_runtime.h>
#include <hip/hip_fp16.h>

// GRU 2-layer, B=256 S=1024 F=75 H=256.
// Round 8: (1) self-validating TAGGED exchange — publish h as u32 (half|tag<<16),
//  poll the data itself (min-u32 tag check), no flags/drain/separate-gather:
//  ONE MALL round trip per phase on the critical path. Parity dbuf + tag==p+1
//  (skew<=1 proof) + per-launch hx memset (replay tags would collide at p=1024).
//  (2) weight-VGPR residency FORCED by aliasing: hcat/xs/ctile/red overwrite the
//  LDS weight bytes after the hoist -> remat illegal. Verify: LDS ~84KB, VGPR>=200.

#define NS 1024
#define NF 75
#define NH 256

#define W0S 360   // halves: 96(x pad) + 256(h) + 8 pad
#define W1S 520   // 256(h0) + 256(h1) + 8 pad
#define HCS 520   // hcat row halves
#define XSS 104   // 96 + 8 pad

#define W0_HALVES (48 * W0S)                 // 17280
#define W1_HALVES (48 * W1S)                 // 24960
#define IMG_HALVES (W0_HALVES + W1_HALVES)   // 42240 halves = 84480 B

// shared aliasing offsets (bytes): loop structs overlay the weight staging area
#define HCAT_OFF 0          // 16*520*2 = 16640
#define XS_OFF   16640      // 2*16*104*2 = 6656 -> 23296
#define CT_OFF   23296      // 8*64*4*4  = 8192 -> 31488
#define RED_OFF  31488      // 16*17*4   = 1088 -> 32576  (< 84480)

// d_ws layout (bytes)
#define WIMG_OFF 0
#define WIMG_BYTES (16 * IMG_HALVES * 2)     // 1,351,680 (16B-aligned)
#define HX0_OFF WIMG_BYTES
#define HX_WORDS (2 * 16 * 16 * 256)         // u32 per array (2 parities) = 131072
#define HX1_OFF (HX0_OFF + HX_WORDS * 4)
#define HX_TOTAL_BYTES (2 * HX_WORDS * 4)    // 1 MiB

typedef _Float16 f16x8 __attribute__((ext_vector_type(8)));
typedef float f32x4 __attribute__((ext_vector_type(4)));
typedef unsigned int u32x4 __attribute__((ext_vector_type(4)));

#define PINV(x) asm volatile("" : "+v"(x))

// MALL-routed coherent ops (sc0 sc1): placement-independent (R4/R5/R7-proven)
__device__ __forceinline__ void st_u32_sys(unsigned* p, unsigned v) {
  asm volatile("global_store_dword %0, %1, off sc0 sc1" :: "v"(p), "v"(v) : "memory");
}
__device__ __forceinline__ void ld_2rows_sys(const unsigned* p0, const unsigned* p1,
    u32x4& a0, u32x4& a1, u32x4& a2, u32x4& a3,
    u32x4& b0, u32x4& b1, u32x4& b2, u32x4& b3) {
  asm volatile(
      "global_load_dwordx4 %0, %8, off sc0 sc1\n\t"
      "global_load_dwordx4 %1, %8, off offset:16 sc0 sc1\n\t"
      "global_load_dwordx4 %2, %8, off offset:32 sc0 sc1\n\t"
      "global_load_dwordx4 %3, %8, off offset:48 sc0 sc1\n\t"
      "global_load_dwordx4 %4, %9, off sc0 sc1\n\t"
      "global_load_dwordx4 %5, %9, off offset:16 sc0 sc1\n\t"
      "global_load_dwordx4 %6, %9, off offset:32 sc0 sc1\n\t"
      "global_load_dwordx4 %7, %9, off offset:48 sc0 sc1\n\t"
      "s_waitcnt vmcnt(0)"
      : "=&v"(a0), "=&v"(a1), "=&v"(a2), "=&v"(a3),
        "=&v"(b0), "=&v"(b1), "=&v"(b2), "=&v"(b3)
      : "v"(p0), "v"(p1) : "memory");
}

// Weight image per block j (halves): W0 [48][W0S] (x cols 0..74, h cols 96..351),
// W1 [48][W1S] (h0 cols 0..255, h1 cols 256..511); row = gate*16+u.
__global__ void prep_wimg(const float* __restrict__ wih0, const float* __restrict__ whh0,
                          const float* __restrict__ wih1, const float* __restrict__ whh1,
                          _Float16* __restrict__ wimg) {
  const int total = 16 * IMG_HALVES;
  for (int i = blockIdx.x * blockDim.x + threadIdx.x; i < total;
       i += gridDim.x * blockDim.x) {
    const int j = i / IMG_HALVES;
    int rem = i - j * IMG_HALVES;
    float val = 0.f;
    if (rem < W0_HALVES) {
      const int row = rem / W0S, k = rem - row * W0S;
      const int gate = row >> 4, u = row & 15;
      const int grow = gate * NH + j * 16 + u;
      if (k < NF) val = wih0[grow * NF + k];
      else if (k >= 96 && k < 352) val = whh0[grow * NH + (k - 96)];
    } else {
      rem -= W0_HALVES;
      const int row = rem / W1S, k = rem - row * W1S;
      const int gate = row >> 4, u = row & 15;
      const int grow = gate * NH + j * 16 + u;
      if (k < 256) val = wih1[grow * NH + k];
      else if (k < 512) val = whh1[grow * NH + (k - 256)];
    }
    wimg[i] = (_Float16)val;
  }
}

__global__ __launch_bounds__(256, 1) void gru_mfma(
    const float* __restrict__ x,
    const float* __restrict__ b_ih0, const float* __restrict__ b_hh0,
    const float* __restrict__ b_ih1, const float* __restrict__ b_hh1,
    const float* __restrict__ w_lin, const float* __restrict__ b_lin,
    const _Float16* __restrict__ wimg,
    unsigned* __restrict__ hx0, unsigned* __restrict__ hx1,
    float* __restrict__ out)
{
  const int tid = threadIdx.x;
  const int bid = blockIdx.x;
  const int gr = (bid & 7) + ((bid >> 7) << 3);   // grouping heuristic (perf-only)
  const int j  = (bid >> 3) & 15;

  // ONE aliased shared region: weight staging first, loop structs overlay it.
  __shared__ f16x8 smem8[IMG_HALVES / 8];          // 84480 B, 16B aligned
  _Float16* Wst  = (_Float16*)smem8;
  _Float16* hcat = (_Float16*)((char*)smem8 + HCAT_OFF);
  _Float16* xs   = (_Float16*)((char*)smem8 + XS_OFF);
  float (*ctile)[64][4] = (float(*)[64][4])((char*)smem8 + CT_OFF);
  float (*red)[17]      = (float(*)[17])((char*)smem8 + RED_OFF);

  int dead = 0, spins = 0;

  // ---- stage weight image into LDS ----
  {
    const float4* src = (const float4*)(wimg + (size_t)j * IMG_HALVES);
    float4* dst = (float4*)Wst;
    for (int i = tid; i < IMG_HALVES / 8; i += 256) dst[i] = src[i];
  }

  const int row = tid >> 4, u = tid & 15, gu = j * 16 + u;
  const int wid = tid >> 6, lane = tid & 63;
  const int lrow = lane & 15, lko = (lane >> 4) * 8;

  const float br0 = b_ih0[gu] + b_hh0[gu];
  const float bz0 = b_ih0[NH + gu] + b_hh0[NH + gu];
  const float bnx0 = b_ih0[2 * NH + gu], bnh0 = b_hh0[2 * NH + gu];
  const float br1 = b_ih1[gu] + b_hh1[gu];
  const float bz1 = b_ih1[NH + gu] + b_hh1[NH + gu];
  const float bnx1 = b_ih1[2 * NH + gu], bnh1 = b_hh1[2 * NH + gu];

  __syncthreads();   // Sa: weight image staged

  // ---- hoist loop-invariant B-fragments to VGPRs ----
  _Float16* W0s = Wst;
  _Float16* W1s = Wst + W0_HALVES;
  f16x8 Bw[11], Bn[16];
  if (wid == 0) {            // L0-r (ct0) + L1-nx (ct6)
    const _Float16* wb = W0s + lrow * W0S + lko;
    #pragma unroll
    for (int i = 0; i < 11; ++i) { Bw[i] = *(const f16x8*)(wb + i * 32); PINV(Bw[i]); }
    const _Float16* wn = W1s + (32 + lrow) * W1S + lko;
    #pragma unroll
    for (int i = 0; i < 8; ++i) { Bn[i] = *(const f16x8*)(wn + i * 32); PINV(Bn[i]); }
  } else if (wid == 1) {     // L0-z (ct1) + L1-nh (ct7)
    const _Float16* wb = W0s + (16 + lrow) * W0S + lko;
    #pragma unroll
    for (int i = 0; i < 11; ++i) { Bw[i] = *(const f16x8*)(wb + i * 32); PINV(Bw[i]); }
    const _Float16* wn = W1s + (32 + lrow) * W1S + lko;
    #pragma unroll
    for (int i = 0; i < 8; ++i) { Bn[i] = *(const f16x8*)(wn + (8 + i) * 32); PINV(Bn[i]); }
  } else if (wid == 2) {     // L0-nx (ct2) + L1-r (ct4)
    const _Float16* wb = W0s + (32 + lrow) * W0S + lko;
    #pragma unroll
    for (int i = 0; i < 3; ++i) { Bw[i] = *(const f16x8*)(wb + i * 32); PINV(Bw[i]); }
    const _Float16* wn = W1s + lrow * W1S + lko;
    #pragma unroll
    for (int i = 0; i < 16; ++i) { Bn[i] = *(const f16x8*)(wn + i * 32); PINV(Bn[i]); }
  } else {                   // L0-nh (ct3) + L1-z (ct5)
    const _Float16* wb = W0s + (32 + lrow) * W0S + lko;
    #pragma unroll
    for (int i = 0; i < 8; ++i) { Bw[i] = *(const f16x8*)(wb + (3 + i) * 32); PINV(Bw[i]); }
    const _Float16* wn = W1s + (16 + lrow) * W1S + lko;
    #pragma unroll
    for (int i = 0; i < 16; ++i) { Bn[i] = *(const f16x8*)(wn + i * 32); PINV(Bn[i]); }
  }
  __syncthreads();   // Sb: all hoist reads done — weight bytes may now be clobbered

  // ---- init loop structs OVER the weight region (clobber => no remat) ----
  for (int i = tid; i < 16 * HCS; i += 256) hcat[i] = (_Float16)0.f;
  for (int i = tid; i < 2 * 16 * XSS; i += 256) xs[i] = (_Float16)0.f;

  int xr_[5], xc_[5]; bool xv_[5];
  #pragma unroll
  for (int i = 0; i < 5; ++i) {
    const int idx = i * 256 + tid;
    xv_[i] = idx < 16 * NF;
    xr_[i] = xv_[i] ? idx / NF : 0;
    xc_[i] = xv_[i] ? idx % NF : 0;
  }
  const float* __restrict__ xbase = x + (size_t)(gr * 16) * NS * NF;
  #pragma unroll
  for (int i = 0; i < 5; ++i)
    if (xv_[i]) xs[xr_[i] * XSS + xc_[i]] =
        (_Float16)xbase[(size_t)xr_[i] * NS * NF + xc_[i]];

  float h0f = 0.f, h1f = 0.f;
  __syncthreads();   // Sc: hcat/xs(t=0) ready

  for (int p = 0; p <= NS; ++p) {
    const int par = p & 1;
    const unsigned tg = (unsigned)(p + 1);

    // 1. next-x prefetch
    float xf[5];
    if (p + 1 < NS) {
      #pragma unroll
      for (int i = 0; i < 5; ++i)
        if (xv_[i]) xf[i] = xbase[((size_t)xr_[i] * NS + (p + 1)) * NF + xc_[i]];
    }

    // 2. A-fragments from LDS
    const _Float16* __restrict__ xp = xs + par * (16 * XSS) + lrow * XSS + lko;
    const _Float16* __restrict__ hp = hcat + lrow * HCS + lko;
    f16x8 xa0{}, xa1{}, xa2{};
    if (wid != 3) {
      xa0 = *(const f16x8*)(xp);
      xa1 = *(const f16x8*)(xp + 32);
      xa2 = *(const f16x8*)(xp + 64);
    }
    f16x8 hfr[16];
    #pragma unroll
    for (int kb = 0; kb < 8; ++kb) hfr[kb] = *(const f16x8*)(hp + kb * 32);
    if (wid != 0) {
      #pragma unroll
      for (int kb = 8; kb < 16; ++kb) hfr[kb] = *(const f16x8*)(hp + kb * 32);
    }

    // 3. L0 MFMA tiles (ct0..3)
    {
      f32x4 accA = {0.f, 0.f, 0.f, 0.f};
      if (wid <= 1) {
        accA = __builtin_amdgcn_mfma_f32_16x16x32_f16(xa0, Bw[0], accA, 0, 0, 0);
        accA = __builtin_amdgcn_mfma_f32_16x16x32_f16(xa1, Bw[1], accA, 0, 0, 0);
        accA = __builtin_amdgcn_mfma_f32_16x16x32_f16(xa2, Bw[2], accA, 0, 0, 0);
        #pragma unroll
        for (int kb = 0; kb < 8; ++kb)
          accA = __builtin_amdgcn_mfma_f32_16x16x32_f16(hfr[kb], Bw[3 + kb], accA, 0, 0, 0);
        *(f32x4*)&ctile[wid][lane][0] = accA;
      } else if (wid == 2) {
        accA = __builtin_amdgcn_mfma_f32_16x16x32_f16(xa0, Bw[0], accA, 0, 0, 0);
        accA = __builtin_amdgcn_mfma_f32_16x16x32_f16(xa1, Bw[1], accA, 0, 0, 0);
        accA = __builtin_amdgcn_mfma_f32_16x16x32_f16(xa2, Bw[2], accA, 0, 0, 0);
        *(f32x4*)&ctile[2][lane][0] = accA;
      } else {
        #pragma unroll
        for (int kb = 0; kb < 8; ++kb)
          accA = __builtin_amdgcn_mfma_f32_16x16x32_f16(hfr[kb], Bw[kb], accA, 0, 0, 0);
        *(f32x4*)&ctile[3][lane][0] = accA;
      }
    }
    __syncthreads();  // S1: ct0..3 ready; all hcat/xs reads done

    // 4. h0 gate + tagged publish (commits under L1 MFMA)
    const int li = ((row >> 2) << 4) | u, rg = row & 3;
    if (p < NS) {
      const float ar = ctile[0][li][rg] + br0;
      const float az = ctile[1][li][rg] + bz0;
      const float nx = ctile[2][li][rg] + bnx0;
      const float nh = ctile[3][li][rg] + bnh0;
      const float r = 1.f / (1.f + __expf(-ar));
      const float z = 1.f / (1.f + __expf(-az));
      const float n = tanhf(nx + r * nh);
      h0f = (1.f - z) * n + z * h0f;
    }
    {
      union { _Float16 h; unsigned short s; } c; c.h = (_Float16)h0f;
      st_u32_sys(hx0 + par * 65536 + gr * 4096 + row * 256 + gu,
                 (unsigned)c.s | (tg << 16));
    }

    // 5. L1 MFMA tiles (ct4..7)
    {
      f32x4 accB = {0.f, 0.f, 0.f, 0.f};
      if (wid == 0) {
        #pragma unroll
        for (int kb = 0; kb < 8; ++kb)
          accB = __builtin_amdgcn_mfma_f32_16x16x32_f16(hfr[kb], Bn[kb], accB, 0, 0, 0);
        *(f32x4*)&ctile[6][lane][0] = accB;
      } else if (wid == 1) {
        #pragma unroll
        for (int kb = 0; kb < 8; ++kb)
          accB = __builtin_amdgcn_mfma_f32_16x16x32_f16(hfr[8 + kb], Bn[kb], accB, 0, 0, 0);
        *(f32x4*)&ctile[7][lane][0] = accB;
      } else {
        #pragma unroll
        for (int kb = 0; kb < 16; ++kb)
          accB = __builtin_amdgcn_mfma_f32_16x16x32_f16(hfr[kb], Bn[kb], accB, 0, 0, 0);
        *(f32x4*)&ctile[2 + wid][lane][0] = accB;   // wid2->4, wid3->5
      }
    }
    __syncthreads();  // S2: ct4..7 ready

    // 6. h1 gate + tagged publish
    if (p >= 1) {
      const float ar = ctile[4][li][rg] + br1;
      const float az = ctile[5][li][rg] + bz1;
      const float nx = ctile[6][li][rg] + bnx1;
      const float nh = ctile[7][li][rg] + bnh1;
      const float r = 1.f / (1.f + __expf(-ar));
      const float z = 1.f / (1.f + __expf(-az));
      const float n = tanhf(nx + r * nh);
      h1f = (1.f - z) * n + z * h1f;
    }
    {
      union { _Float16 h; unsigned short s; } c; c.h = (_Float16)h1f;
      st_u32_sys(hx1 + par * 65536 + gr * 4096 + row * 256 + gu,
                 (unsigned)c.s | (tg << 16));
    }

    // 7. stage x[t+1]
    if (p + 1 < NS) {
      #pragma unroll
      for (int i = 0; i < 5; ++i)
        if (xv_[i]) xs[((p + 1) & 1) * (16 * XSS) + xr_[i] * XSS + xc_[i]] =
            (_Float16)xf[i];
    }

    // 8. self-validating poll-gather: ONE round trip, no flags, no drain
    {
      const int mj = tid & 15, rr = tid >> 4;
      const int off = par * 65536 + gr * 4096 + rr * 256 + mj * 16;
      const unsigned* b0p = hx0 + off;
      const unsigned* b1p = hx1 + off;
      u32x4 A0, A1, A2, A3, B0, B1, B2, B3;
      for (;;) {
        ld_2rows_sys(b0p, b1p, A0, A1, A2, A3, B0, B1, B2, B3);
        u32x4 m4 = __builtin_elementwise_min(
            __builtin_elementwise_min(__builtin_elementwise_min(A0, A1),
                                      __builtin_elementwise_min(A2, A3)),
            __builtin_elementwise_min(__builtin_elementwise_min(B0, B1),
                                      __builtin_elementwise_min(B2, B3)));
        unsigned m = m4.x;
        m = m4.y < m ? m4.y : m;
        m = m4.z < m ? m4.z : m;
        m = m4.w < m ? m4.w : m;
        if ((m >> 16) == tg) break;          // all 32 tags fresh (min-tag trick)
        if (++spins > 200000) { dead = 1; break; }
        __builtin_amdgcn_s_sleep(1);
      }
      _Float16* h0d = hcat + rr * HCS + mj * 16;
      _Float16* h1d = h0d + 256;
      *(unsigned*)(h0d + 0)  = (A0.x & 0xffffu) | (A0.y << 16);
      *(unsigned*)(h0d + 2)  = (A0.z & 0xffffu) | (A0.w << 16);
      *(unsigned*)(h0d + 4)  = (A1.x & 0xffffu) | (A1.y << 16);
      *(unsigned*)(h0d + 6)  = (A1.z & 0xffffu) | (A1.w << 16);
      *(unsigned*)(h0d + 8)  = (A2.x & 0xffffu) | (A2.y << 16);
      *(unsigned*)(h0d + 10) = (A2.z & 0xffffu) | (A2.w << 16);
      *(unsigned*)(h0d + 12) = (A3.x & 0xffffu) | (A3.y << 16);
      *(unsigned*)(h0d + 14) = (A3.z & 0xffffu) | (A3.w << 16);
      *(unsigned*)(h1d + 0)  = (B0.x & 0xffffu) | (B0.y << 16);
      *(unsigned*)(h1d + 2)  = (B0.z & 0xffffu) | (B0.w << 16);
      *(unsigned*)(h1d + 4)  = (B1.x & 0xffffu) | (B1.y << 16);
      *(unsigned*)(h1d + 6)  = (B1.z & 0xffffu) | (B1.w << 16);
      *(unsigned*)(h1d + 8)  = (B2.x & 0xffffu) | (B2.y << 16);
      *(unsigned*)(h1d + 10) = (B2.z & 0xffffu) | (B2.w << 16);
      *(unsigned*)(h1d + 12) = (B3.x & 0xffffu) | (B3.y << 16);
      *(unsigned*)(h1d + 14) = (B3.z & 0xffffu) | (B3.w << 16);
    }
    __syncthreads();  // S4: hcat ready for next phase
  }

  // ---- final linear ----
  {
    float part = 0.f;
    #pragma unroll
    for (int e = 0; e < 16; ++e)
      part += (float)hcat[row * HCS + 256 + u * 16 + e] * w_lin[u * 16 + e];
    red[row][u] = part;
    __syncthreads();
    if (j == 0 && tid < 16) {
      float s = 0.f;
      #pragma unroll
      for (int e = 0; e < 16; ++e) s += red[tid][e];
      out[gr * 16 + tid] = s + b_lin[0];
    }
  }
}

extern "C" void kernel_launch(void* const* d_in, const int* in_sizes, int n_in,
                              void* d_out, int out_size, void* d_ws, size_t ws_size,
                              hipStream_t stream) {
  (void)in_sizes; (void)n_in; (void)out_size; (void)ws_size;
  const float* x     = (const float*)d_in[0];
  const float* w_ih0 = (const float*)d_in[1];
  const float* w_hh0 = (const float*)d_in[2];
  const float* b_ih0 = (const float*)d_in[3];
  const float* b_hh0 = (const float*)d_in[4];
  const float* w_ih1 = (const float*)d_in[5];
  const float* w_hh1 = (const float*)d_in[6];
  const float* b_ih1 = (const float*)d_in[7];
  const float* b_hh1 = (const float*)d_in[8];
  const float* w_lin = (const float*)d_in[9];
  const float* b_lin = (const float*)d_in[10];

  char* ws = (char*)d_ws;
  _Float16* wimg = (_Float16*)(ws + WIMG_OFF);
  unsigned* hx0  = (unsigned*)(ws + HX0_OFF);
  unsigned* hx1  = (unsigned*)(ws + HX1_OFF);

  // Clear tag space every launch (stale tags from a previous replay would
  // exactly collide at p=1024; poison 0xAAAA never equals a live tag).
  hipMemsetAsync(ws + HX0_OFF, 0, HX_TOTAL_BYTES, stream);
  prep_wimg<<<1024, 256, 0, stream>>>(w_ih0, w_hh0, w_ih1, w_hh1, wimg);
  gru_mfma<<<256, 256, 0, stream>>>(x, b_ih0, b_hh0, b_ih1, b_hh1,
                                    w_lin, b_lin, wimg, hx0, hx1,
                                    (float*)d_out);
}